// Round 5
// baseline (723.677 us; speedup 1.0000x reference)
//
#include <hip/hip_runtime.h>

#define N_NODES 50000
#define N_EDGES 800000
#define DIM 128
#define N_LAYERS 3

// fixed-capacity bucket: 64 ushort slots/node (128 B = exactly 2 lines).
// In-degree ~ Poisson(16); P(>64) ~ 1e-20. src ids < 50000 fit ushort.
#define CAP_LOG2 6
#define CAP (1 << CAP_LOG2)

typedef __attribute__((ext_vector_type(8))) short bf16x8;
typedef __attribute__((ext_vector_type(4))) float f32x4;

__device__ __forceinline__ unsigned short f2bf(float f) {
    unsigned int u = __float_as_uint(f);
    u += 0x7fffu + ((u >> 16) & 1u);   // RNE
    return (unsigned short)(u >> 16);
}
__device__ __forceinline__ float bfu2f_lo(unsigned int v) { return __uint_as_float(v << 16); }
__device__ __forceinline__ float bfu2f_hi(unsigned int v) { return __uint_as_float(v & 0xffff0000u); }

// ---------------- build (XCD-partitioned) + cvt ----------------
// Build floor = the 800k rank atomics (~43 µs, invariant under ILP x4/x8,
// overlay, nt on/off, ushort). Frozen.

#define NODE_RANGE ((N_NODES + 7) / 8)        // 6250 nodes per XCD range
#define EDGES_PER_BLOCK 2048                  // 256 thr x 8 edges
#define BUILD_CH ((N_EDGES + EDGES_PER_BLOCK - 1) / EDGES_PER_BLOCK)   // 391 chunks
#define BUILD_NB (BUILD_CH * 8)               // 3128 blocks
#define CVT_X_T (N_NODES * (DIM / 4))         // 1,600,000 float4s
#define CVT_W_T (6 * DIM * DIM)               // 98,304
#define CVT_NB  ((CVT_X_T + CVT_W_T + 255) / 256)   // 6634

__global__ void build_cvt_kernel(const int* __restrict__ src, const int* __restrict__ dst,
                                 int* __restrict__ counts, unsigned short* __restrict__ srcs_sorted,
                                 const float* __restrict__ x, unsigned short* __restrict__ z,
                                 const float* __restrict__ Ws1, const float* __restrict__ Ws2,
                                 unsigned short* __restrict__ wt) {
    if (blockIdx.x < BUILD_NB) {
        int r = blockIdx.x & 7;               // dst range; aligns with XCD round-robin dispatch
        int c = blockIdx.x >> 3;              // edge chunk
        int lo = r * NODE_RANGE;
        int hi = lo + NODE_RANGE;
        int base = c * EDGES_PER_BLOCK;
#pragma unroll
        for (int j = 0; j < 8; ++j) {
            int e = base + j * 256 + threadIdx.x;
            if (e < N_EDGES) {
                int d = dst[e];
                if (d >= lo && d < hi) {
                    int s = src[e];
                    int rk = atomicAdd(&counts[d], 1);
                    if (rk < CAP) srcs_sorted[(d << CAP_LOG2) + rk] = (unsigned short)s;
                }
            }
        }
    } else {
        int t = (blockIdx.x - BUILD_NB) * 256 + threadIdx.x;
        if (t < CVT_X_T) {
            float4 v = ((const float4*)x)[t];
            ushort4 o;
            o.x = f2bf(v.x); o.y = f2bf(v.y); o.z = f2bf(v.z); o.w = f2bf(v.w);
            ((ushort4*)z)[t] = o;
        } else if (t - CVT_X_T < CVT_W_T) {
            int u = t - CVT_X_T;
            int m = u >> 14;
            int r2 = u & 16383;
            int n = r2 >> 7;
            int k = r2 & 127;
            const float* Wm = (m < 3) ? (Ws1 + (size_t)m * DIM * DIM)
                                      : (Ws2 + (size_t)(m - 3) * DIM * DIM);
            wt[u] = f2bf(Wm[(size_t)k * DIM + n]);   // WT[m][n][k]
        }
    }
}

// ---------------- gather: one full wave aggregates one node ----------------
// Verbatim proven loop: sub = lane>>4, col = lane&15; 16-edge main loop keeps
// 4 uint4 row loads in flight per lane; zero intra-wave divergence (e is
// wave-uniform). Writes the node's bf16 row into LDS (hrow) from sub==0.

__device__ __forceinline__ void gather_node(int node, const uint4* __restrict__ zp,
                                            const unsigned int* __restrict__ sp,
                                            const int* __restrict__ counts,
                                            const unsigned short* __restrict__ srcs,
                                            int sub, int col, unsigned short* hrow) {
    float a0 = 0.f, a1 = 0.f, a2 = 0.f, a3 = 0.f, a4 = 0.f, a5 = 0.f, a6 = 0.f, a7 = 0.f;
    float b0 = 0.f, b1 = 0.f, b2 = 0.f, b3 = 0.f, b4 = 0.f, b5 = 0.f, b6 = 0.f, b7 = 0.f;

    int s = node << CAP_LOG2;                     // slot base (even)
    int deg = counts[node];
    if (deg > CAP) deg = CAP;
    int e = s + deg;
    int i = s;
    // 16-edge main loop: 2 pair loads, 4 uint4 row loads in flight per lane
    for (; i + 16 <= e; i += 16) {
        unsigned int p0 = sp[(i >> 1) + sub];         // edges i+2sub, i+2sub+1
        unsigned int p1 = sp[(i >> 1) + 4 + sub];     // edges i+8+2sub, i+8+2sub+1
        int eA0 = (int)(p0 & 0xffffu), eB0 = (int)(p0 >> 16);
        int eA1 = (int)(p1 & 0xffffu), eB1 = (int)(p1 >> 16);
        uint4 vA0 = zp[(size_t)eA0 * 16 + col];
        uint4 vB0 = zp[(size_t)eB0 * 16 + col];
        uint4 vA1 = zp[(size_t)eA1 * 16 + col];
        uint4 vB1 = zp[(size_t)eB1 * 16 + col];
        a0 += bfu2f_lo(vA0.x); a1 += bfu2f_hi(vA0.x); a2 += bfu2f_lo(vA0.y); a3 += bfu2f_hi(vA0.y);
        a4 += bfu2f_lo(vA0.z); a5 += bfu2f_hi(vA0.z); a6 += bfu2f_lo(vA0.w); a7 += bfu2f_hi(vA0.w);
        b0 += bfu2f_lo(vB0.x); b1 += bfu2f_hi(vB0.x); b2 += bfu2f_lo(vB0.y); b3 += bfu2f_hi(vB0.y);
        b4 += bfu2f_lo(vB0.z); b5 += bfu2f_hi(vB0.z); b6 += bfu2f_lo(vB0.w); b7 += bfu2f_hi(vB0.w);
        a0 += bfu2f_lo(vA1.x); a1 += bfu2f_hi(vA1.x); a2 += bfu2f_lo(vA1.y); a3 += bfu2f_hi(vA1.y);
        a4 += bfu2f_lo(vA1.z); a5 += bfu2f_hi(vA1.z); a6 += bfu2f_lo(vA1.w); a7 += bfu2f_hi(vA1.w);
        b0 += bfu2f_lo(vB1.x); b1 += bfu2f_hi(vB1.x); b2 += bfu2f_lo(vB1.y); b3 += bfu2f_hi(vB1.y);
        b4 += bfu2f_lo(vB1.z); b5 += bfu2f_hi(vB1.z); b6 += bfu2f_lo(vB1.w); b7 += bfu2f_hi(vB1.w);
    }
    for (; i + 8 <= e; i += 8) {
        unsigned int pair = sp[(i >> 1) + sub];
        int eA = (int)(pair & 0xffffu);
        int eB = (int)(pair >> 16);
        uint4 vA = zp[(size_t)eA * 16 + col];
        uint4 vB = zp[(size_t)eB * 16 + col];
        a0 += bfu2f_lo(vA.x); a1 += bfu2f_hi(vA.x); a2 += bfu2f_lo(vA.y); a3 += bfu2f_hi(vA.y);
        a4 += bfu2f_lo(vA.z); a5 += bfu2f_hi(vA.z); a6 += bfu2f_lo(vA.w); a7 += bfu2f_hi(vA.w);
        b0 += bfu2f_lo(vB.x); b1 += bfu2f_hi(vB.x); b2 += bfu2f_lo(vB.y); b3 += bfu2f_hi(vB.y);
        b4 += bfu2f_lo(vB.z); b5 += bfu2f_hi(vB.z); b6 += bfu2f_lo(vB.w); b7 += bfu2f_hi(vB.w);
    }
    // tail (0..7 edges): sub handles slots i+2*sub and i+2*sub+1 if in range
    {
        int j0 = i + sub * 2;
        if (j0 < e) {
            int eA = (int)srcs[j0];
            uint4 vA = zp[(size_t)eA * 16 + col];
            a0 += bfu2f_lo(vA.x); a1 += bfu2f_hi(vA.x); a2 += bfu2f_lo(vA.y); a3 += bfu2f_hi(vA.y);
            a4 += bfu2f_lo(vA.z); a5 += bfu2f_hi(vA.z); a6 += bfu2f_lo(vA.w); a7 += bfu2f_hi(vA.w);
        }
        if (j0 + 1 < e) {
            int eB = (int)srcs[j0 + 1];
            uint4 vB = zp[(size_t)eB * 16 + col];
            b0 += bfu2f_lo(vB.x); b1 += bfu2f_hi(vB.x); b2 += bfu2f_lo(vB.y); b3 += bfu2f_hi(vB.y);
            b4 += bfu2f_lo(vB.z); b5 += bfu2f_hi(vB.z); b6 += bfu2f_lo(vB.w); b7 += bfu2f_hi(vB.w);
        }
    }

    a0 += b0; a1 += b1; a2 += b2; a3 += b3; a4 += b4; a5 += b5; a6 += b6; a7 += b7;
    a0 += __shfl_xor(a0, 16); a1 += __shfl_xor(a1, 16); a2 += __shfl_xor(a2, 16); a3 += __shfl_xor(a3, 16);
    a4 += __shfl_xor(a4, 16); a5 += __shfl_xor(a5, 16); a6 += __shfl_xor(a6, 16); a7 += __shfl_xor(a7, 16);
    a0 += __shfl_xor(a0, 32); a1 += __shfl_xor(a1, 32); a2 += __shfl_xor(a2, 32); a3 += __shfl_xor(a3, 32);
    a4 += __shfl_xor(a4, 32); a5 += __shfl_xor(a5, 32); a6 += __shfl_xor(a6, 32); a7 += __shfl_xor(a7, 32);

    // self term (eps = 0)
    uint4 sv = zp[(size_t)node * 16 + col];
    a0 += bfu2f_lo(sv.x); a1 += bfu2f_hi(sv.x); a2 += bfu2f_lo(sv.y); a3 += bfu2f_hi(sv.y);
    a4 += bfu2f_lo(sv.z); a5 += bfu2f_hi(sv.z); a6 += bfu2f_lo(sv.w); a7 += bfu2f_hi(sv.w);

    if (sub == 0) {
        unsigned short* hp = hrow + col * 8;      // 8 B aligned (stride 264 B)
        ((unsigned int*)hp)[0] = (unsigned int)f2bf(a0) | ((unsigned int)f2bf(a1) << 16);
        ((unsigned int*)hp)[1] = (unsigned int)f2bf(a2) | ((unsigned int)f2bf(a3) << 16);
        ((unsigned int*)(hp + 4))[0] = (unsigned int)f2bf(a4) | ((unsigned int)f2bf(a5) << 16);
        ((unsigned int*)(hp + 4))[1] = (unsigned int)f2bf(a6) | ((unsigned int)f2bf(a7) << 16);
    }
}

// ---------------- persistent 3-layer kernel ----------------
// Verified R2 pipeline (57 µs/layer, passed) wrapped in a 3-iteration layer
// loop with a grid barrier between layers. Co-residency is guaranteed by
// exact capacity: 1024 blocks x 512 thr = 4 blocks/CU x 256 CU = 2048 thr/CU
// (HW max); VGPR <= 64 via __launch_bounds__(512,8) (R2 compiled at 32);
// LDS 12.8 KB x 4 = 51 KB < 160 KB. Removes 2 inter-layer dispatch gaps.
// Barrier: one single-use arrive counter per boundary (no reset/sense),
// AGENT-scope acq/rel atomics give cross-XCD L2 visibility of z writes.

#define TILE 16
#define T_STRIDE 132
#define NT_TILES (N_NODES / TILE)   // 3125, exact
#define GRID_L 1024                 // 4 blocks/CU, all co-resident

__device__ __forceinline__ void grid_barrier(unsigned int* ctr) {
    __syncthreads();                 // all block's prior LDS/global work done locally
    if (threadIdx.x == 0) {
        __hip_atomic_fetch_add(ctr, 1u, __ATOMIC_ACQ_REL, __HIP_MEMORY_SCOPE_AGENT);
        while (__hip_atomic_load(ctr, __ATOMIC_ACQUIRE, __HIP_MEMORY_SCOPE_AGENT) < GRID_L) {
            __builtin_amdgcn_s_sleep(1);
        }
    }
    __syncthreads();
}

__global__ __launch_bounds__(512, 8) void gin3_kernel(const unsigned short* __restrict__ zA,
                                                      unsigned short* __restrict__ zB,
                                                      const int* __restrict__ counts,
                                                      const unsigned short* __restrict__ srcs,
                                                      const unsigned short* __restrict__ wt,
                                                      const float* __restrict__ bs1,
                                                      const float* __restrict__ bs2,
                                                      float* __restrict__ outp,
                                                      unsigned int* __restrict__ bars) {
    __shared__ unsigned short hbuf[2][TILE * T_STRIDE];   // double-buffered agg rows
    __shared__ unsigned short t_lds[TILE * T_STRIDE];     // MLP intermediate

    const unsigned int* sp = (const unsigned int*)srcs;   // 2 indices per uint

    int wave = threadIdx.x >> 6;     // 0..7
    int lane = threadIdx.x & 63;
    int sub  = lane >> 4;            // gather sub-slot / MLP quad
    int col  = lane & 15;            // gather col / MLP r16
    int c    = wave * 16 + col;      // MLP output column (8 waves x 16 = 128)

    for (int l = 0; l < N_LAYERS; ++l) {
        const unsigned short* zin = (l == 0) ? zA : ((l == 1) ? zB : zA);
        unsigned short* zbf = (l == 0) ? zB : (unsigned short*)zA;  // bf16 dst (l<2)
        const bool last = (l == N_LAYERS - 1);
        const uint4* zp = (const uint4*)zin;              // row stride = 16 uint4
        const unsigned short* WT1 = wt + (size_t)l * DIM * DIM;
        const unsigned short* WT2 = wt + (size_t)(3 + l) * DIM * DIM;
        const float* b1 = bs1 + (size_t)l * DIM;
        const float* b2 = bs2 + (size_t)l * DIM;

        int t = blockIdx.x;          // tile being gathered
        int tm = -1;                 // tile being MLP'd
        int pg = 0;                  // hbuf parity gather writes to

        while (t < NT_TILES || tm >= 0) {
            bool hasG = (t < NT_TILES);
            unsigned short* hw = hbuf[pg];
            const unsigned short* hr = hbuf[pg ^ 1];

            // ---- Phase A: MLP stage1(tm) + gather node t*16+wave ----
            if (tm >= 0) {
                f32x4 acc;
#pragma unroll
                for (int ii = 0; ii < 4; ++ii) acc[ii] = 0.f;
#pragma unroll
                for (int ks = 0; ks < 4; ++ks) {
                    int k = ks * 32 + sub * 8;
                    bf16x8 a = *(const bf16x8*)&hr[col * T_STRIDE + k];
                    bf16x8 b = *(const bf16x8*)(WT1 + (size_t)c * DIM + k);
                    acc = __builtin_amdgcn_mfma_f32_16x16x32_bf16(a, b, acc, 0, 0, 0);
                }
                float bv = b1[c];
#pragma unroll
                for (int ii = 0; ii < 4; ++ii)
                    t_lds[(sub * 4 + ii) * T_STRIDE + c] = f2bf(fmaxf(acc[ii] + bv, 0.f));
            }
            if (hasG)
                gather_node(t * TILE + wave, zp, sp, counts, srcs, sub, col,
                            &hw[wave * T_STRIDE]);
            __syncthreads();

            // ---- Phase B: MLP stage2(tm) + gather node t*16+8+wave ----
            if (tm >= 0) {
                f32x4 acc2;
#pragma unroll
                for (int ii = 0; ii < 4; ++ii) acc2[ii] = 0.f;
#pragma unroll
                for (int ks = 0; ks < 4; ++ks) {
                    int k = ks * 32 + sub * 8;
                    bf16x8 a = *(const bf16x8*)&t_lds[col * T_STRIDE + k];
                    bf16x8 b = *(const bf16x8*)(WT2 + (size_t)c * DIM + k);
                    acc2 = __builtin_amdgcn_mfma_f32_16x16x32_bf16(a, b, acc2, 0, 0, 0);
                }
                float bv = b2[c];
#pragma unroll
                for (int ii = 0; ii < 4; ++ii) {
                    int row = tm * TILE + sub * 4 + ii;   // always < N_NODES (exact tiling)
                    float v = fmaxf(acc2[ii] + bv, 0.f);
                    if (last) __builtin_nontemporal_store(v, &outp[(size_t)row * DIM + c]);
                    else zbf[(size_t)row * DIM + c] = f2bf(v);
                }
            }
            if (hasG)
                gather_node(t * TILE + 8 + wave, zp, sp, counts, srcs, sub, col,
                            &hw[(8 + wave) * T_STRIDE]);
            __syncthreads();

            tm = hasG ? t : -1;
            pg ^= 1;
            t += GRID_L;
        }

        if (l < N_LAYERS - 1) grid_barrier(&bars[l]);
    }
}

// ---------------- launch ----------------

extern "C" void kernel_launch(void* const* d_in, const int* in_sizes, int n_in,
                              void* d_out, int out_size, void* d_ws, size_t ws_size,
                              hipStream_t stream) {
    const float* x   = (const float*)d_in[0];
    const float* Ws1 = (const float*)d_in[1];
    const float* bs1 = (const float*)d_in[2];
    const float* Ws2 = (const float*)d_in[3];
    const float* bs2 = (const float*)d_in[4];
    const int*   ei  = (const int*)d_in[5];   // int32 (JAX x64 disabled)
    const int* src = ei;
    const int* dst = ei + N_EDGES;
    float* out = (float*)d_out;

    char* ws = (char*)d_ws;
    size_t off = 0;
    auto carve = [&](size_t bytes) {
        void* p = ws + off;
        off += (bytes + 255) & ~(size_t)255;
        return p;
    };
    unsigned short* zA   = (unsigned short*)carve((size_t)N_NODES * DIM * 2);
    unsigned short* zB   = (unsigned short*)carve((size_t)N_NODES * DIM * 2);
    unsigned short* wt   = (unsigned short*)carve((size_t)6 * DIM * DIM * 2);
    int* counts = (int*)carve((size_t)N_NODES * 4);       // 200000 B -> padded 200192
    unsigned int* bars = (unsigned int*)carve(256);       // adjacent: one memset covers both
    unsigned short* srcs = (unsigned short*)carve((size_t)N_NODES * CAP * 2);   // 6.4 MB buckets

    // zero counts + barrier counters in ONE memset (adjacent carves)
    size_t zero_bytes = (((size_t)N_NODES * 4 + 255) & ~(size_t)255) + 256;
    hipMemsetAsync(counts, 0, zero_bytes, stream);

    // build (XCD-partitioned hist+scatter) + cvt
    build_cvt_kernel<<<BUILD_NB + CVT_NB, 256, 0, stream>>>(src, dst, counts, srcs,
                                                            x, zA, Ws1, Ws2, wt);

    // all three layers in one persistent dispatch
    gin3_kernel<<<GRID_L, 512, 0, stream>>>(zA, zB, counts, srcs, wt, bs1, bs2, out, bars);
}

// Round 6
// 696.282 us; speedup vs baseline: 1.0393x; 1.0393x over previous
//
#include <hip/hip_runtime.h>

#define N_NODES 50000
#define N_EDGES 800000
#define DIM 128
#define N_LAYERS 3

// fixed-capacity bucket: 64 ushort slots/node (128 B = exactly 2 lines).
// In-degree ~ Poisson(16); P(>64) ~ 1e-20. src ids < 50000 fit ushort.
#define CAP_LOG2 6
#define CAP (1 << CAP_LOG2)

typedef __attribute__((ext_vector_type(8))) short bf16x8;
typedef __attribute__((ext_vector_type(4))) float f32x4;

__device__ __forceinline__ unsigned short f2bf(float f) {
    unsigned int u = __float_as_uint(f);
    u += 0x7fffu + ((u >> 16) & 1u);   // RNE
    return (unsigned short)(u >> 16);
}
__device__ __forceinline__ float bfu2f_lo(unsigned int v) { return __uint_as_float(v << 16); }
__device__ __forceinline__ float bfu2f_hi(unsigned int v) { return __uint_as_float(v & 0xffff0000u); }

#define NODE_RANGE ((N_NODES + 7) / 8)        // 6250 nodes per XCD range
#define CVT_X_T (N_NODES * (DIM / 4))         // 1,600,000 float4s
#define CVT_W_T (6 * DIM * DIM)               // 98,304
#define EDGES_PER_GROUP (N_EDGES / 128)       // 6250, exact

#define TILE 16
#define T_STRIDE 132
#define NT_TILES (N_NODES / TILE)   // 3125, exact
#define GRID_L 1024                 // 4 blocks/CU x 256 CU, all co-resident (proven R5)

// ---------------- grid barrier (fixed) ----------------
// R5 bug: ACQUIRE poll -> buffer_inv per iteration -> 1024 pollers nuke the
// XCD L2s continuously -> working stragglers lose all L2 hits -> ~230 µs/bar.
// Fix: RELAXED polls (read-through, no inv) + s_sleep backoff; exactly ONE
// RELEASE add on arrival (wb of this block's z writes) and ONE ACQUIRE load
// on exit (single inv; covers the block's CU-L1 + XCD-L2 for all its waves).

__device__ __forceinline__ void grid_barrier(unsigned int* ctr) {
    __syncthreads();                 // block's prior global work issued
    if (threadIdx.x == 0) {
        __hip_atomic_fetch_add(ctr, 1u, __ATOMIC_RELEASE, __HIP_MEMORY_SCOPE_AGENT);
        while (__hip_atomic_load(ctr, __ATOMIC_RELAXED, __HIP_MEMORY_SCOPE_AGENT) < GRID_L)
            __builtin_amdgcn_s_sleep(32);
        (void)__hip_atomic_load(ctr, __ATOMIC_ACQUIRE, __HIP_MEMORY_SCOPE_AGENT);
    }
    __syncthreads();
}

// ---------------- gather: one full wave aggregates one node ----------------
// Verbatim proven loop (R2, passed): sub = lane>>4, col = lane&15; 16-edge
// main loop keeps 4 uint4 row loads in flight per lane; zero intra-wave
// divergence. Writes the node's bf16 row into LDS (hrow) from sub==0.

__device__ __forceinline__ void gather_node(int node, const uint4* __restrict__ zp,
                                            const unsigned int* __restrict__ sp,
                                            const int* __restrict__ counts,
                                            const unsigned short* __restrict__ srcs,
                                            int sub, int col, unsigned short* hrow) {
    float a0 = 0.f, a1 = 0.f, a2 = 0.f, a3 = 0.f, a4 = 0.f, a5 = 0.f, a6 = 0.f, a7 = 0.f;
    float b0 = 0.f, b1 = 0.f, b2 = 0.f, b3 = 0.f, b4 = 0.f, b5 = 0.f, b6 = 0.f, b7 = 0.f;

    int s = node << CAP_LOG2;                     // slot base (even)
    int deg = counts[node];
    if (deg > CAP) deg = CAP;
    int e = s + deg;
    int i = s;
    // 16-edge main loop: 2 pair loads, 4 uint4 row loads in flight per lane
    for (; i + 16 <= e; i += 16) {
        unsigned int p0 = sp[(i >> 1) + sub];         // edges i+2sub, i+2sub+1
        unsigned int p1 = sp[(i >> 1) + 4 + sub];     // edges i+8+2sub, i+8+2sub+1
        int eA0 = (int)(p0 & 0xffffu), eB0 = (int)(p0 >> 16);
        int eA1 = (int)(p1 & 0xffffu), eB1 = (int)(p1 >> 16);
        uint4 vA0 = zp[(size_t)eA0 * 16 + col];
        uint4 vB0 = zp[(size_t)eB0 * 16 + col];
        uint4 vA1 = zp[(size_t)eA1 * 16 + col];
        uint4 vB1 = zp[(size_t)eB1 * 16 + col];
        a0 += bfu2f_lo(vA0.x); a1 += bfu2f_hi(vA0.x); a2 += bfu2f_lo(vA0.y); a3 += bfu2f_hi(vA0.y);
        a4 += bfu2f_lo(vA0.z); a5 += bfu2f_hi(vA0.z); a6 += bfu2f_lo(vA0.w); a7 += bfu2f_hi(vA0.w);
        b0 += bfu2f_lo(vB0.x); b1 += bfu2f_hi(vB0.x); b2 += bfu2f_lo(vB0.y); b3 += bfu2f_hi(vB0.y);
        b4 += bfu2f_lo(vB0.z); b5 += bfu2f_hi(vB0.z); b6 += bfu2f_lo(vB0.w); b7 += bfu2f_hi(vB0.w);
        a0 += bfu2f_lo(vA1.x); a1 += bfu2f_hi(vA1.x); a2 += bfu2f_lo(vA1.y); a3 += bfu2f_hi(vA1.y);
        a4 += bfu2f_lo(vA1.z); a5 += bfu2f_hi(vA1.z); a6 += bfu2f_lo(vA1.w); a7 += bfu2f_hi(vA1.w);
        b0 += bfu2f_lo(vB1.x); b1 += bfu2f_hi(vB1.x); b2 += bfu2f_lo(vB1.y); b3 += bfu2f_hi(vB1.y);
        b4 += bfu2f_lo(vB1.z); b5 += bfu2f_hi(vB1.z); b6 += bfu2f_lo(vB1.w); b7 += bfu2f_hi(vB1.w);
    }
    for (; i + 8 <= e; i += 8) {
        unsigned int pair = sp[(i >> 1) + sub];
        int eA = (int)(pair & 0xffffu);
        int eB = (int)(pair >> 16);
        uint4 vA = zp[(size_t)eA * 16 + col];
        uint4 vB = zp[(size_t)eB * 16 + col];
        a0 += bfu2f_lo(vA.x); a1 += bfu2f_hi(vA.x); a2 += bfu2f_lo(vA.y); a3 += bfu2f_hi(vA.y);
        a4 += bfu2f_lo(vA.z); a5 += bfu2f_hi(vA.z); a6 += bfu2f_lo(vA.w); a7 += bfu2f_hi(vA.w);
        b0 += bfu2f_lo(vB.x); b1 += bfu2f_hi(vB.x); b2 += bfu2f_lo(vB.y); b3 += bfu2f_hi(vB.y);
        b4 += bfu2f_lo(vB.z); b5 += bfu2f_hi(vB.z); b6 += bfu2f_lo(vB.w); b7 += bfu2f_hi(vB.w);
    }
    // tail (0..7 edges): sub handles slots i+2*sub and i+2*sub+1 if in range
    {
        int j0 = i + sub * 2;
        if (j0 < e) {
            int eA = (int)srcs[j0];
            uint4 vA = zp[(size_t)eA * 16 + col];
            a0 += bfu2f_lo(vA.x); a1 += bfu2f_hi(vA.x); a2 += bfu2f_lo(vA.y); a3 += bfu2f_hi(vA.y);
            a4 += bfu2f_lo(vA.z); a5 += bfu2f_hi(vA.z); a6 += bfu2f_lo(vA.w); a7 += bfu2f_hi(vA.w);
        }
        if (j0 + 1 < e) {
            int eB = (int)srcs[j0 + 1];
            uint4 vB = zp[(size_t)eB * 16 + col];
            b0 += bfu2f_lo(vB.x); b1 += bfu2f_hi(vB.x); b2 += bfu2f_lo(vB.y); b3 += bfu2f_hi(vB.y);
            b4 += bfu2f_lo(vB.z); b5 += bfu2f_hi(vB.z); b6 += bfu2f_lo(vB.w); b7 += bfu2f_hi(vB.w);
        }
    }

    a0 += b0; a1 += b1; a2 += b2; a3 += b3; a4 += b4; a5 += b5; a6 += b6; a7 += b7;
    a0 += __shfl_xor(a0, 16); a1 += __shfl_xor(a1, 16); a2 += __shfl_xor(a2, 16); a3 += __shfl_xor(a3, 16);
    a4 += __shfl_xor(a4, 16); a5 += __shfl_xor(a5, 16); a6 += __shfl_xor(a6, 16); a7 += __shfl_xor(a7, 16);
    a0 += __shfl_xor(a0, 32); a1 += __shfl_xor(a1, 32); a2 += __shfl_xor(a2, 32); a3 += __shfl_xor(a3, 32);
    a4 += __shfl_xor(a4, 32); a5 += __shfl_xor(a5, 32); a6 += __shfl_xor(a6, 32); a7 += __shfl_xor(a7, 32);

    // self term (eps = 0)
    uint4 sv = zp[(size_t)node * 16 + col];
    a0 += bfu2f_lo(sv.x); a1 += bfu2f_hi(sv.x); a2 += bfu2f_lo(sv.y); a3 += bfu2f_hi(sv.y);
    a4 += bfu2f_lo(sv.z); a5 += bfu2f_hi(sv.z); a6 += bfu2f_lo(sv.w); a7 += bfu2f_hi(sv.w);

    if (sub == 0) {
        unsigned short* hp = hrow + col * 8;      // 8 B aligned (stride 264 B)
        ((unsigned int*)hp)[0] = (unsigned int)f2bf(a0) | ((unsigned int)f2bf(a1) << 16);
        ((unsigned int*)hp)[1] = (unsigned int)f2bf(a2) | ((unsigned int)f2bf(a3) << 16);
        ((unsigned int*)(hp + 4))[0] = (unsigned int)f2bf(a4) | ((unsigned int)f2bf(a5) << 16);
        ((unsigned int*)(hp + 4))[1] = (unsigned int)f2bf(a6) | ((unsigned int)f2bf(a7) << 16);
    }
}

// ---------------- everything in ONE persistent kernel ----------------
// Phase 0: build (XCD-aligned: 1024 % 8 == 0 preserves blockIdx&7 = range) +
//          cvt (grid-stride), then grid barrier.
// Layers: verified R2 pipeline (gather t || MLP t-1, 2 phases, 2 barriers),
//         tiles from a dynamic work queue (thread-0 grab in phase A, LDS
//         broadcast, consumed next iteration) -> no 4-vs-3 tile imbalance.
// ctrl[]: [0..2] = per-layer tile queues, [16..18] = barrier counters.

__global__ __launch_bounds__(512, 8) void gin_all(const int* __restrict__ src,
                                                  const int* __restrict__ dst,
                                                  int* __restrict__ counts,
                                                  unsigned short* __restrict__ srcs,
                                                  const float* __restrict__ x,
                                                  unsigned short* __restrict__ zA,
                                                  unsigned short* __restrict__ zB,
                                                  const float* __restrict__ Ws1,
                                                  const float* __restrict__ Ws2,
                                                  unsigned short* __restrict__ wt,
                                                  const float* __restrict__ bs1,
                                                  const float* __restrict__ bs2,
                                                  float* __restrict__ outp,
                                                  unsigned int* __restrict__ ctrl) {
    __shared__ unsigned short hbuf[2][TILE * T_STRIDE];   // double-buffered agg rows
    __shared__ unsigned short t_lds[TILE * T_STRIDE];     // MLP intermediate
    __shared__ int next_t;

    const unsigned int* sp = (const unsigned int*)srcs;   // 2 indices per uint

    int wave = threadIdx.x >> 6;     // 0..7
    int lane = threadIdx.x & 63;
    int sub  = lane >> 4;            // gather sub-slot / MLP quad
    int col  = lane & 15;            // gather col / MLP r16
    int c    = wave * 16 + col;      // MLP output column (8 waves x 16 = 128)

    // ---- phase 0: build + cvt ----
    {
        int r = blockIdx.x & 7;               // dst range = XCD (1024 % 8 == 0)
        int g = blockIdx.x >> 3;              // edge group 0..127
        int lo = r * NODE_RANGE;
        int hi = lo + NODE_RANGE;
        int base = g * EDGES_PER_GROUP;
        int lim = base + EDGES_PER_GROUP;
#pragma unroll
        for (int j = 0; j < 13; ++j) {        // 13*512 >= 6250
            int e = base + j * 512 + (int)threadIdx.x;
            if (e < lim) {
                int d = dst[e];
                if (d >= lo && d < hi) {
                    int s = src[e];
                    int rk = atomicAdd(&counts[d], 1);
                    if (rk < CAP) srcs[(d << CAP_LOG2) + rk] = (unsigned short)s;
                }
            }
        }
        const int tot = CVT_X_T + CVT_W_T;
        for (int u = blockIdx.x * 512 + (int)threadIdx.x; u < tot; u += GRID_L * 512) {
            if (u < CVT_X_T) {
                float4 v = ((const float4*)x)[u];
                ushort4 o;
                o.x = f2bf(v.x); o.y = f2bf(v.y); o.z = f2bf(v.z); o.w = f2bf(v.w);
                ((ushort4*)zA)[u] = o;
            } else {
                int w = u - CVT_X_T;
                int m = w >> 14;
                int r2 = w & 16383;
                int n = r2 >> 7;
                int k = r2 & 127;
                const float* Wm = (m < 3) ? (Ws1 + (size_t)m * DIM * DIM)
                                          : (Ws2 + (size_t)(m - 3) * DIM * DIM);
                wt[w] = f2bf(Wm[(size_t)k * DIM + n]);   // WT[m][n][k]
            }
        }
    }
    grid_barrier(&ctrl[16]);

    // ---- 3 layers ----
    for (int l = 0; l < N_LAYERS; ++l) {
        const unsigned short* zin = (l == 0) ? zA : ((l == 1) ? zB : zA);
        unsigned short* zbf = (l == 0) ? zB : zA;     // bf16 dst for l < 2
        const bool last = (l == N_LAYERS - 1);
        const uint4* zp = (const uint4*)zin;          // row stride = 16 uint4
        const unsigned short* WT1 = wt + (size_t)l * DIM * DIM;
        const unsigned short* WT2 = wt + (size_t)(3 + l) * DIM * DIM;
        const float* b1 = bs1 + (size_t)l * DIM;
        const float* b2 = bs2 + (size_t)l * DIM;
        unsigned int* wq = &ctrl[l];

        if (threadIdx.x == 0) next_t = (int)atomicAdd(wq, 1u);
        __syncthreads();
        int t = next_t;                  // first grabs cover 0..1023
        int tm = -1;                     // tile being MLP'd
        int pg = 0;                      // hbuf parity gather writes to

        while (t < NT_TILES || tm >= 0) {
            bool hasG = (t < NT_TILES);
            unsigned short* hw = hbuf[pg];
            const unsigned short* hr = hbuf[pg ^ 1];

            // ---- Phase A: queue-grab + MLP stage1(tm) + gather node t*16+wave ----
            if (threadIdx.x == 0 && hasG) next_t = (int)atomicAdd(wq, 1u);
            if (tm >= 0) {
                f32x4 acc;
#pragma unroll
                for (int ii = 0; ii < 4; ++ii) acc[ii] = 0.f;
#pragma unroll
                for (int ks = 0; ks < 4; ++ks) {
                    int k = ks * 32 + sub * 8;
                    bf16x8 a = *(const bf16x8*)&hr[col * T_STRIDE + k];
                    bf16x8 b = *(const bf16x8*)(WT1 + (size_t)c * DIM + k);
                    acc = __builtin_amdgcn_mfma_f32_16x16x32_bf16(a, b, acc, 0, 0, 0);
                }
                float bv = b1[c];
#pragma unroll
                for (int ii = 0; ii < 4; ++ii)
                    t_lds[(sub * 4 + ii) * T_STRIDE + c] = f2bf(fmaxf(acc[ii] + bv, 0.f));
            }
            if (hasG)
                gather_node(t * TILE + wave, zp, sp, counts, srcs, sub, col,
                            &hw[wave * T_STRIDE]);
            __syncthreads();

            // ---- Phase B: MLP stage2(tm) + gather node t*16+8+wave ----
            int t_new = hasG ? next_t : NT_TILES;   // read before B's barrier
            if (tm >= 0) {
                f32x4 acc2;
#pragma unroll
                for (int ii = 0; ii < 4; ++ii) acc2[ii] = 0.f;
#pragma unroll
                for (int ks = 0; ks < 4; ++ks) {
                    int k = ks * 32 + sub * 8;
                    bf16x8 a = *(const bf16x8*)&t_lds[col * T_STRIDE + k];
                    bf16x8 b = *(const bf16x8*)(WT2 + (size_t)c * DIM + k);
                    acc2 = __builtin_amdgcn_mfma_f32_16x16x32_bf16(a, b, acc2, 0, 0, 0);
                }
                float bv = b2[c];
#pragma unroll
                for (int ii = 0; ii < 4; ++ii) {
                    int row = tm * TILE + sub * 4 + ii;   // always < N_NODES (exact tiling)
                    float v = fmaxf(acc2[ii] + bv, 0.f);
                    if (last) __builtin_nontemporal_store(v, &outp[(size_t)row * DIM + c]);
                    else zbf[(size_t)row * DIM + c] = f2bf(v);
                }
            }
            if (hasG)
                gather_node(t * TILE + 8 + wave, zp, sp, counts, srcs, sub, col,
                            &hw[(8 + wave) * T_STRIDE]);
            __syncthreads();

            tm = hasG ? t : -1;
            pg ^= 1;
            t = t_new;
        }

        if (l < N_LAYERS - 1) grid_barrier(&ctrl[17 + l]);
    }
}

// ---------------- launch ----------------

extern "C" void kernel_launch(void* const* d_in, const int* in_sizes, int n_in,
                              void* d_out, int out_size, void* d_ws, size_t ws_size,
                              hipStream_t stream) {
    const float* x   = (const float*)d_in[0];
    const float* Ws1 = (const float*)d_in[1];
    const float* bs1 = (const float*)d_in[2];
    const float* Ws2 = (const float*)d_in[3];
    const float* bs2 = (const float*)d_in[4];
    const int*   ei  = (const int*)d_in[5];   // int32 (JAX x64 disabled)
    const int* src = ei;
    const int* dst = ei + N_EDGES;
    float* out = (float*)d_out;

    char* ws = (char*)d_ws;
    size_t off = 0;
    auto carve = [&](size_t bytes) {
        void* p = ws + off;
        off += (bytes + 255) & ~(size_t)255;
        return p;
    };
    unsigned short* zA   = (unsigned short*)carve((size_t)N_NODES * DIM * 2);
    unsigned short* zB   = (unsigned short*)carve((size_t)N_NODES * DIM * 2);
    unsigned short* wt   = (unsigned short*)carve((size_t)6 * DIM * DIM * 2);
    int* counts = (int*)carve((size_t)N_NODES * 4);       // padded to 200192
    unsigned int* ctrl = (unsigned int*)carve(256);       // adjacent: one memset covers both
    unsigned short* srcs = (unsigned short*)carve((size_t)N_NODES * CAP * 2);   // 6.4 MB buckets

    // zero counts + work-queue/barrier counters in ONE memset (adjacent carves)
    size_t zero_bytes = (((size_t)N_NODES * 4 + 255) & ~(size_t)255) + 256;
    hipMemsetAsync(counts, 0, zero_bytes, stream);

    // single persistent dispatch: build + cvt + 3 fused layers
    gin_all<<<GRID_L, 512, 0, stream>>>(src, dst, counts, srcs, x, zA, zB,
                                        Ws1, Ws2, wt, bs1, bs2, out, ctrl);
}

// Round 8
// 311.172 us; speedup vs baseline: 2.3257x; 2.2376x over previous
//
#include <hip/hip_runtime.h>

#define N_NODES 50000
#define N_EDGES 800000
#define DIM 128
#define N_LAYERS 3

// fixed-capacity bucket: 64 ushort slots/node (128 B = exactly 2 lines).
// In-degree ~ Poisson(16); P(>64) ~ 1e-20. src ids < 50000 fit ushort.
#define CAP_LOG2 6
#define CAP (1 << CAP_LOG2)

typedef __attribute__((ext_vector_type(8))) short bf16x8;
typedef __attribute__((ext_vector_type(4))) float f32x4;

__device__ __forceinline__ unsigned short f2bf(float f) {
    unsigned int u = __float_as_uint(f);
    u += 0x7fffu + ((u >> 16) & 1u);   // RNE
    return (unsigned short)(u >> 16);
}
__device__ __forceinline__ float bfu2f_lo(unsigned int v) { return __uint_as_float(v << 16); }
__device__ __forceinline__ float bfu2f_hi(unsigned int v) { return __uint_as_float(v & 0xffff0000u); }

// ---------------- build (XCD-partitioned) + cvt ----------------
// Build floor = the 800k rank atomics (~43 µs, invariant under ILP x4/x8,
// overlay, nt on/off, ushort). Frozen.

#define NODE_RANGE ((N_NODES + 7) / 8)        // 6250 nodes per XCD range
#define EDGES_PER_BLOCK 2048                  // 256 thr x 8 edges
#define BUILD_CH ((N_EDGES + EDGES_PER_BLOCK - 1) / EDGES_PER_BLOCK)   // 391 chunks
#define BUILD_NB (BUILD_CH * 8)               // 3128 blocks
#define CVT_X_T (N_NODES * (DIM / 4))         // 1,600,000 float4s
#define CVT_W_T (6 * DIM * DIM)               // 98,304
#define CVT_NB  ((CVT_X_T + CVT_W_T + 255) / 256)   // 6634

__global__ void build_cvt_kernel(const int* __restrict__ src, const int* __restrict__ dst,
                                 int* __restrict__ counts, unsigned short* __restrict__ srcs_sorted,
                                 const float* __restrict__ x, unsigned short* __restrict__ z,
                                 const float* __restrict__ Ws1, const float* __restrict__ Ws2,
                                 unsigned short* __restrict__ wt) {
    if (blockIdx.x < BUILD_NB) {
        int r = blockIdx.x & 7;               // dst range; aligns with XCD round-robin dispatch
        int c = blockIdx.x >> 3;              // edge chunk
        int lo = r * NODE_RANGE;
        int hi = lo + NODE_RANGE;
        int base = c * EDGES_PER_BLOCK;
#pragma unroll
        for (int j = 0; j < 8; ++j) {
            int e = base + j * 256 + threadIdx.x;
            if (e < N_EDGES) {
                int d = dst[e];
                if (d >= lo && d < hi) {
                    int s = src[e];
                    int rk = atomicAdd(&counts[d], 1);
                    if (rk < CAP) srcs_sorted[(d << CAP_LOG2) + rk] = (unsigned short)s;
                }
            }
        }
    } else {
        int t = (blockIdx.x - BUILD_NB) * 256 + threadIdx.x;
        if (t < CVT_X_T) {
            float4 v = ((const float4*)x)[t];
            ushort4 o;
            o.x = f2bf(v.x); o.y = f2bf(v.y); o.z = f2bf(v.z); o.w = f2bf(v.w);
            ((ushort4*)z)[t] = o;
        } else if (t - CVT_X_T < CVT_W_T) {
            int u = t - CVT_X_T;
            int m = u >> 14;
            int r2 = u & 16383;
            int n = r2 >> 7;
            int k = r2 & 127;
            const float* Wm = (m < 3) ? (Ws1 + (size_t)m * DIM * DIM)
                                      : (Ws2 + (size_t)(m - 3) * DIM * DIM);
            wt[u] = f2bf(Wm[(size_t)k * DIM + n]);   // WT[m][n][k]
        }
    }
}

// ---------------- gather2: one wave aggregates TWO nodes, interleaved -------
// Two independent dependency chains (pair->rows for A and B) double the
// useful miss-ILP vs the single-node loop, and node A's serial phases (pair
// latency, reduce) overlap node B's loads. Self rows are issued FIRST so
// their ~600-cycle miss latency hides under the entire edge loop.
// 8 accumulators per node (dep distance 8 instrs > 4-cyc VALU latency) keeps
// the whole function + MLP within 64 VGPR -> 4 blocks/CU preserved.
// Slot mapping per node is identical to the verified loop: sub handles slots
// {i+2sub, i+2sub+1} per 8-edge chunk; xor16+xor32 reduce over subs.

#define ACC8(f, v) \
    f##0 += bfu2f_lo((v).x); f##1 += bfu2f_hi((v).x); \
    f##2 += bfu2f_lo((v).y); f##3 += bfu2f_hi((v).y); \
    f##4 += bfu2f_lo((v).z); f##5 += bfu2f_hi((v).z); \
    f##6 += bfu2f_lo((v).w); f##7 += bfu2f_hi((v).w);

__device__ __forceinline__ void gather2(int nA, int nB, const uint4* __restrict__ zp,
                                        const unsigned int* __restrict__ sp,
                                        const int* __restrict__ counts,
                                        const unsigned short* __restrict__ srcs,
                                        int sub, int col,
                                        unsigned short* rowA, unsigned short* rowB) {
    uint4 svA = zp[(size_t)nA * 16 + col];   // self rows: in flight across the
    uint4 svB = zp[(size_t)nB * 16 + col];   // whole edge loop (used after reduce)

    float fA0 = 0.f, fA1 = 0.f, fA2 = 0.f, fA3 = 0.f, fA4 = 0.f, fA5 = 0.f, fA6 = 0.f, fA7 = 0.f;
    float fB0 = 0.f, fB1 = 0.f, fB2 = 0.f, fB3 = 0.f, fB4 = 0.f, fB5 = 0.f, fB6 = 0.f, fB7 = 0.f;

    int iA = nA << CAP_LOG2;
    int dA = counts[nA]; if (dA > CAP) dA = CAP;
    int eA = iA + dA;
    int iB = nB << CAP_LOG2;
    int dB = counts[nB]; if (dB > CAP) dB = CAP;
    int eB = iB + dB;

    // joint main loop: 8 edges per node per iter; 2 pair + 4 row loads in
    // flight from two independent chains (all loop bounds wave-uniform)
    while (iA + 8 <= eA && iB + 8 <= eB) {
        unsigned int pA = sp[(iA >> 1) + sub];
        unsigned int pB = sp[(iB >> 1) + sub];
        int a0 = (int)(pA & 0xffffu), a1 = (int)(pA >> 16);
        int b0 = (int)(pB & 0xffffu), b1 = (int)(pB >> 16);
        uint4 vA0 = zp[(size_t)a0 * 16 + col];
        uint4 vB0 = zp[(size_t)b0 * 16 + col];
        uint4 vA1 = zp[(size_t)a1 * 16 + col];
        uint4 vB1 = zp[(size_t)b1 * 16 + col];
        ACC8(fA, vA0); ACC8(fB, vB0); ACC8(fA, vA1); ACC8(fB, vB1);
        iA += 8; iB += 8;
    }
    while (iA + 8 <= eA) {           // drain A
        unsigned int pA = sp[(iA >> 1) + sub];
        int a0 = (int)(pA & 0xffffu), a1 = (int)(pA >> 16);
        uint4 vA0 = zp[(size_t)a0 * 16 + col];
        uint4 vA1 = zp[(size_t)a1 * 16 + col];
        ACC8(fA, vA0); ACC8(fA, vA1);
        iA += 8;
    }
    while (iB + 8 <= eB) {           // drain B
        unsigned int pB = sp[(iB >> 1) + sub];
        int b0 = (int)(pB & 0xffffu), b1 = (int)(pB >> 16);
        uint4 vB0 = zp[(size_t)b0 * 16 + col];
        uint4 vB1 = zp[(size_t)b1 * 16 + col];
        ACC8(fB, vB0); ACC8(fB, vB1);
        iB += 8;
    }
    // tails (0..7 edges each): sub handles slots i+2sub, i+2sub+1 if in range
    {
        int j0 = iA + sub * 2;
        if (j0 < eA)     { uint4 v = zp[(size_t)(int)srcs[j0]     * 16 + col]; ACC8(fA, v); }
        if (j0 + 1 < eA) { uint4 v = zp[(size_t)(int)srcs[j0 + 1] * 16 + col]; ACC8(fA, v); }
        int k0 = iB + sub * 2;
        if (k0 < eB)     { uint4 v = zp[(size_t)(int)srcs[k0]     * 16 + col]; ACC8(fB, v); }
        if (k0 + 1 < eB) { uint4 v = zp[(size_t)(int)srcs[k0 + 1] * 16 + col]; ACC8(fB, v); }
    }

    // cross-lane reduce over subs (xor16 then xor32), both nodes
    fA0 += __shfl_xor(fA0, 16); fA1 += __shfl_xor(fA1, 16); fA2 += __shfl_xor(fA2, 16); fA3 += __shfl_xor(fA3, 16);
    fA4 += __shfl_xor(fA4, 16); fA5 += __shfl_xor(fA5, 16); fA6 += __shfl_xor(fA6, 16); fA7 += __shfl_xor(fA7, 16);
    fB0 += __shfl_xor(fB0, 16); fB1 += __shfl_xor(fB1, 16); fB2 += __shfl_xor(fB2, 16); fB3 += __shfl_xor(fB3, 16);
    fB4 += __shfl_xor(fB4, 16); fB5 += __shfl_xor(fB5, 16); fB6 += __shfl_xor(fB6, 16); fB7 += __shfl_xor(fB7, 16);
    fA0 += __shfl_xor(fA0, 32); fA1 += __shfl_xor(fA1, 32); fA2 += __shfl_xor(fA2, 32); fA3 += __shfl_xor(fA3, 32);
    fA4 += __shfl_xor(fA4, 32); fA5 += __shfl_xor(fA5, 32); fA6 += __shfl_xor(fA6, 32); fA7 += __shfl_xor(fA7, 32);
    fB0 += __shfl_xor(fB0, 32); fB1 += __shfl_xor(fB1, 32); fB2 += __shfl_xor(fB2, 32); fB3 += __shfl_xor(fB3, 32);
    fB4 += __shfl_xor(fB4, 32); fB5 += __shfl_xor(fB5, 32); fB6 += __shfl_xor(fB6, 32); fB7 += __shfl_xor(fB7, 32);

    // self terms (eps = 0)
    ACC8(fA, svA);
    ACC8(fB, svB);

    if (sub == 0) {
        unsigned short* hp = rowA + col * 8;      // 8 B aligned (stride 264 B)
        ((unsigned int*)hp)[0] = (unsigned int)f2bf(fA0) | ((unsigned int)f2bf(fA1) << 16);
        ((unsigned int*)hp)[1] = (unsigned int)f2bf(fA2) | ((unsigned int)f2bf(fA3) << 16);
        ((unsigned int*)(hp + 4))[0] = (unsigned int)f2bf(fA4) | ((unsigned int)f2bf(fA5) << 16);
        ((unsigned int*)(hp + 4))[1] = (unsigned int)f2bf(fA6) | ((unsigned int)f2bf(fA7) << 16);
        unsigned short* hq = rowB + col * 8;
        ((unsigned int*)hq)[0] = (unsigned int)f2bf(fB0) | ((unsigned int)f2bf(fB1) << 16);
        ((unsigned int*)hq)[1] = (unsigned int)f2bf(fB2) | ((unsigned int)f2bf(fB3) << 16);
        ((unsigned int*)(hq + 4))[0] = (unsigned int)f2bf(fB4) | ((unsigned int)f2bf(fB5) << 16);
        ((unsigned int*)(hq + 4))[1] = (unsigned int)f2bf(fB6) | ((unsigned int)f2bf(fB7) << 16);
    }
}

// ---------------- pipelined fused layer (R2-verified structure) ----------------
// 512 threads (8 waves), grid 1024 = 4 blocks/CU (32 waves/CU). Block
// pipelines tiles: while MLP'ing tile t-1 it gathers tile t. Phase A now
// gathers BOTH of the wave's nodes via gather2 (doubled miss-ILP); phase B
// is MLP stage2 only. Barriers, MLP code, LDS layout verbatim from R2.

#define TILE 16
#define T_STRIDE 132
#define NT_TILES (N_NODES / TILE)   // 3125, exact
#define GRID_L 1024                 // 4 blocks/CU, all co-resident

template <bool LAST>
__global__ __launch_bounds__(512, 8) void layer_pipe(const unsigned short* __restrict__ z,
                                                     const int* __restrict__ counts,
                                                     const unsigned short* __restrict__ srcs,
                                                     const unsigned short* __restrict__ WT1,
                                                     const float* __restrict__ b1,
                                                     const unsigned short* __restrict__ WT2,
                                                     const float* __restrict__ b2,
                                                     void* __restrict__ Cout) {
    __shared__ unsigned short hbuf[2][TILE * T_STRIDE];   // double-buffered agg rows
    __shared__ unsigned short t_lds[TILE * T_STRIDE];     // MLP intermediate

    const uint4* zp = (const uint4*)z;                    // row stride = 16 uint4
    const unsigned int* sp = (const unsigned int*)srcs;   // 2 indices per uint

    int wave = threadIdx.x >> 6;     // 0..7
    int lane = threadIdx.x & 63;
    int sub  = lane >> 4;            // gather sub-slot / MLP quad
    int col  = lane & 15;            // gather col / MLP r16
    int c    = wave * 16 + col;      // MLP output column (8 waves x 16 = 128)

    int t = blockIdx.x;              // tile being gathered
    int tm = -1;                     // tile being MLP'd
    int pg = 0;                      // hbuf parity gather writes to

    while (t < NT_TILES || tm >= 0) {
        bool hasG = (t < NT_TILES);
        unsigned short* hw = hbuf[pg];
        const unsigned short* hr = hbuf[pg ^ 1];

        // ---- Phase A: MLP stage1(tm) + gather BOTH nodes of t ----
        if (tm >= 0) {
            f32x4 acc;
#pragma unroll
            for (int ii = 0; ii < 4; ++ii) acc[ii] = 0.f;
#pragma unroll
            for (int ks = 0; ks < 4; ++ks) {
                int k = ks * 32 + sub * 8;
                bf16x8 a = *(const bf16x8*)&hr[col * T_STRIDE + k];
                bf16x8 b = *(const bf16x8*)(WT1 + (size_t)c * DIM + k);
                acc = __builtin_amdgcn_mfma_f32_16x16x32_bf16(a, b, acc, 0, 0, 0);
            }
            float bv = b1[c];
#pragma unroll
            for (int ii = 0; ii < 4; ++ii)
                t_lds[(sub * 4 + ii) * T_STRIDE + c] = f2bf(fmaxf(acc[ii] + bv, 0.f));
        }
        if (hasG)
            gather2(t * TILE + wave, t * TILE + 8 + wave, zp, sp, counts, srcs,
                    sub, col, &hw[wave * T_STRIDE], &hw[(8 + wave) * T_STRIDE]);
        __syncthreads();

        // ---- Phase B: MLP stage2(tm) ----
        if (tm >= 0) {
            f32x4 acc2;
#pragma unroll
            for (int ii = 0; ii < 4; ++ii) acc2[ii] = 0.f;
#pragma unroll
            for (int ks = 0; ks < 4; ++ks) {
                int k = ks * 32 + sub * 8;
                bf16x8 a = *(const bf16x8*)&t_lds[col * T_STRIDE + k];
                bf16x8 b = *(const bf16x8*)(WT2 + (size_t)c * DIM + k);
                acc2 = __builtin_amdgcn_mfma_f32_16x16x32_bf16(a, b, acc2, 0, 0, 0);
            }
            float bv = b2[c];
#pragma unroll
            for (int ii = 0; ii < 4; ++ii) {
                int row = tm * TILE + sub * 4 + ii;   // always < N_NODES (exact tiling)
                float v = fmaxf(acc2[ii] + bv, 0.f);
                if (LAST) __builtin_nontemporal_store(v, &((float*)Cout)[(size_t)row * DIM + c]);
                else ((unsigned short*)Cout)[(size_t)row * DIM + c] = f2bf(v);
            }
        }
        __syncthreads();

        tm = hasG ? t : -1;
        pg ^= 1;
        t += GRID_L;
    }
}

// ---------------- launch ----------------

extern "C" void kernel_launch(void* const* d_in, const int* in_sizes, int n_in,
                              void* d_out, int out_size, void* d_ws, size_t ws_size,
                              hipStream_t stream) {
    const float* x   = (const float*)d_in[0];
    const float* Ws1 = (const float*)d_in[1];
    const float* bs1 = (const float*)d_in[2];
    const float* Ws2 = (const float*)d_in[3];
    const float* bs2 = (const float*)d_in[4];
    const int*   ei  = (const int*)d_in[5];   // int32 (JAX x64 disabled)
    const int* src = ei;
    const int* dst = ei + N_EDGES;
    float* out = (float*)d_out;

    char* ws = (char*)d_ws;
    size_t off = 0;
    auto carve = [&](size_t bytes) {
        void* p = ws + off;
        off += (bytes + 255) & ~(size_t)255;
        return p;
    };
    unsigned short* zA   = (unsigned short*)carve((size_t)N_NODES * DIM * 2);
    unsigned short* zB   = (unsigned short*)carve((size_t)N_NODES * DIM * 2);
    unsigned short* wt   = (unsigned short*)carve((size_t)6 * DIM * DIM * 2);
    int* counts = (int*)carve((size_t)N_NODES * 4);
    unsigned short* srcs = (unsigned short*)carve((size_t)N_NODES * CAP * 2);   // 6.4 MB buckets

    // build (XCD-partitioned hist+scatter) + cvt
    hipMemsetAsync(counts, 0, (size_t)N_NODES * 4, stream);
    build_cvt_kernel<<<BUILD_NB + CVT_NB, 256, 0, stream>>>(src, dst, counts, srcs,
                                                            x, zA, Ws1, Ws2, wt);

    unsigned short* zin = zA;
    unsigned short* znext = zB;
    for (int l = 0; l < N_LAYERS; ++l) {
        if (l == N_LAYERS - 1) {
            layer_pipe<true><<<GRID_L, 512, 0, stream>>>(
                zin, counts, srcs, wt + (size_t)l * DIM * DIM, bs1 + (size_t)l * DIM,
                wt + (size_t)(3 + l) * DIM * DIM, bs2 + (size_t)l * DIM, out);
        } else {
            layer_pipe<false><<<GRID_L, 512, 0, stream>>>(
                zin, counts, srcs, wt + (size_t)l * DIM * DIM, bs1 + (size_t)l * DIM,
                wt + (size_t)(3 + l) * DIM * DIM, bs2 + (size_t)l * DIM, znext);
            unsigned short* tmp = zin; zin = znext; znext = tmp;
        }
    }
}

// Round 9
// 275.329 us; speedup vs baseline: 2.6284x; 1.1302x over previous
//
#include <hip/hip_runtime.h>

#define N_NODES 50000
#define N_EDGES 800000
#define DIM 128
#define N_LAYERS 3

// fixed-capacity bucket: 64 ushort slots/node (128 B = exactly 2 lines).
// In-degree ~ Poisson(16); P(>64) ~ 1e-20. src ids < 50000 fit ushort.
#define CAP_LOG2 6
#define CAP (1 << CAP_LOG2)

typedef __attribute__((ext_vector_type(8))) short bf16x8;
typedef __attribute__((ext_vector_type(4))) float f32x4;

__device__ __forceinline__ unsigned short f2bf(float f) {
    unsigned int u = __float_as_uint(f);
    u += 0x7fffu + ((u >> 16) & 1u);   // RNE
    return (unsigned short)(u >> 16);
}
__device__ __forceinline__ float bfu2f_lo(unsigned int v) { return __uint_as_float(v << 16); }
__device__ __forceinline__ float bfu2f_hi(unsigned int v) { return __uint_as_float(v & 0xffff0000u); }

// ---------------- build (XCD-partitioned) + cvt ----------------
// Build floor = the 800k rank atomics (~43 µs, invariant under ILP x4/x8,
// overlay, nt on/off, ushort). Frozen.

#define NODE_RANGE ((N_NODES + 7) / 8)        // 6250 nodes per XCD range
#define EDGES_PER_BLOCK 2048                  // 256 thr x 8 edges
#define BUILD_CH ((N_EDGES + EDGES_PER_BLOCK - 1) / EDGES_PER_BLOCK)   // 391 chunks
#define BUILD_NB (BUILD_CH * 8)               // 3128 blocks
#define CVT_X_T (N_NODES * (DIM / 4))         // 1,600,000 float4s
#define CVT_W_T (6 * DIM * DIM)               // 98,304
#define CVT_NB  ((CVT_X_T + CVT_W_T + 255) / 256)   // 6634

__global__ void build_cvt_kernel(const int* __restrict__ src, const int* __restrict__ dst,
                                 int* __restrict__ counts, unsigned short* __restrict__ srcs_sorted,
                                 const float* __restrict__ x, unsigned short* __restrict__ z,
                                 const float* __restrict__ Ws1, const float* __restrict__ Ws2,
                                 unsigned short* __restrict__ wt) {
    if (blockIdx.x < BUILD_NB) {
        int r = blockIdx.x & 7;               // dst range; aligns with XCD round-robin dispatch
        int c = blockIdx.x >> 3;              // edge chunk
        int lo = r * NODE_RANGE;
        int hi = lo + NODE_RANGE;
        int base = c * EDGES_PER_BLOCK;
#pragma unroll
        for (int j = 0; j < 8; ++j) {
            int e = base + j * 256 + threadIdx.x;
            if (e < N_EDGES) {
                int d = dst[e];
                if (d >= lo && d < hi) {
                    int s = src[e];
                    int rk = atomicAdd(&counts[d], 1);
                    if (rk < CAP) srcs_sorted[(d << CAP_LOG2) + rk] = (unsigned short)s;
                }
            }
        }
    } else {
        int t = (blockIdx.x - BUILD_NB) * 256 + threadIdx.x;
        if (t < CVT_X_T) {
            float4 v = ((const float4*)x)[t];
            ushort4 o;
            o.x = f2bf(v.x); o.y = f2bf(v.y); o.z = f2bf(v.z); o.w = f2bf(v.w);
            ((ushort4*)z)[t] = o;
        } else if (t - CVT_X_T < CVT_W_T) {
            int u = t - CVT_X_T;
            int m = u >> 14;
            int r2 = u & 16383;
            int n = r2 >> 7;
            int k = r2 & 127;
            const float* Wm = (m < 3) ? (Ws1 + (size_t)m * DIM * DIM)
                                      : (Ws2 + (size_t)(m - 3) * DIM * DIM);
            wt[u] = f2bf(Wm[(size_t)k * DIM + n]);   // WT[m][n][k]
        }
    }
}

// ---------------- gather2 v2: TWO nodes interleaved, spill-free ----------------
// R8's +28 MB symmetric FETCH/WRITE delta = scratch spill round-trip: the two
// self-rows (8 VGPRs) were held live across the whole edge loop. v2 defers the
// self-row loads to AFTER the edge loop (issued before the 32-instr shuffle
// reduce, which covers their likely-L2-hit latency). Live set in the loop is
// now 16 accums + 4 in-flight rows + 2 pairs + bounds ~= 40 VGPR < 64 cap.
// Slot mapping per node identical to the verified loop.

#define ACC8(f, v) \
    f##0 += bfu2f_lo((v).x); f##1 += bfu2f_hi((v).x); \
    f##2 += bfu2f_lo((v).y); f##3 += bfu2f_hi((v).y); \
    f##4 += bfu2f_lo((v).z); f##5 += bfu2f_hi((v).z); \
    f##6 += bfu2f_lo((v).w); f##7 += bfu2f_hi((v).w);

__device__ __forceinline__ void gather2(int nA, int nB, const uint4* __restrict__ zp,
                                        const unsigned int* __restrict__ sp,
                                        const int* __restrict__ counts,
                                        const unsigned short* __restrict__ srcs,
                                        int sub, int col,
                                        unsigned short* rowA, unsigned short* rowB) {
    float fA0 = 0.f, fA1 = 0.f, fA2 = 0.f, fA3 = 0.f, fA4 = 0.f, fA5 = 0.f, fA6 = 0.f, fA7 = 0.f;
    float fB0 = 0.f, fB1 = 0.f, fB2 = 0.f, fB3 = 0.f, fB4 = 0.f, fB5 = 0.f, fB6 = 0.f, fB7 = 0.f;

    int iA = nA << CAP_LOG2;
    int dA = counts[nA]; if (dA > CAP) dA = CAP;
    int eA = iA + dA;
    int iB = nB << CAP_LOG2;
    int dB = counts[nB]; if (dB > CAP) dB = CAP;
    int eB = iB + dB;

    // joint main loop: 8 edges per node per iter; 2 pair + 4 row loads in
    // flight from two independent chains (all loop bounds wave-uniform)
    while (iA + 8 <= eA && iB + 8 <= eB) {
        unsigned int pA = sp[(iA >> 1) + sub];
        unsigned int pB = sp[(iB >> 1) + sub];
        int a0 = (int)(pA & 0xffffu), a1 = (int)(pA >> 16);
        int b0 = (int)(pB & 0xffffu), b1 = (int)(pB >> 16);
        uint4 vA0 = zp[(size_t)a0 * 16 + col];
        uint4 vB0 = zp[(size_t)b0 * 16 + col];
        uint4 vA1 = zp[(size_t)a1 * 16 + col];
        uint4 vB1 = zp[(size_t)b1 * 16 + col];
        ACC8(fA, vA0); ACC8(fB, vB0); ACC8(fA, vA1); ACC8(fB, vB1);
        iA += 8; iB += 8;
    }
    while (iA + 8 <= eA) {           // drain A
        unsigned int pA = sp[(iA >> 1) + sub];
        int a0 = (int)(pA & 0xffffu), a1 = (int)(pA >> 16);
        uint4 vA0 = zp[(size_t)a0 * 16 + col];
        uint4 vA1 = zp[(size_t)a1 * 16 + col];
        ACC8(fA, vA0); ACC8(fA, vA1);
        iA += 8;
    }
    while (iB + 8 <= eB) {           // drain B
        unsigned int pB = sp[(iB >> 1) + sub];
        int b0 = (int)(pB & 0xffffu), b1 = (int)(pB >> 16);
        uint4 vB0 = zp[(size_t)b0 * 16 + col];
        uint4 vB1 = zp[(size_t)b1 * 16 + col];
        ACC8(fB, vB0); ACC8(fB, vB1);
        iB += 8;
    }
    // tails (0..7 edges each): sub handles slots i+2sub, i+2sub+1 if in range
    {
        int j0 = iA + sub * 2;
        if (j0 < eA)     { uint4 v = zp[(size_t)(int)srcs[j0]     * 16 + col]; ACC8(fA, v); }
        if (j0 + 1 < eA) { uint4 v = zp[(size_t)(int)srcs[j0 + 1] * 16 + col]; ACC8(fA, v); }
        int k0 = iB + sub * 2;
        if (k0 < eB)     { uint4 v = zp[(size_t)(int)srcs[k0]     * 16 + col]; ACC8(fB, v); }
        if (k0 + 1 < eB) { uint4 v = zp[(size_t)(int)srcs[k0 + 1] * 16 + col]; ACC8(fB, v); }
    }

    // self rows: issued here (edge-loop regs retired); latency hides under the
    // 32-instruction shuffle reduce below. Used only after the reduce.
    uint4 svA = zp[(size_t)nA * 16 + col];
    uint4 svB = zp[(size_t)nB * 16 + col];

    // cross-lane reduce over subs (xor16 then xor32), both nodes
    fA0 += __shfl_xor(fA0, 16); fA1 += __shfl_xor(fA1, 16); fA2 += __shfl_xor(fA2, 16); fA3 += __shfl_xor(fA3, 16);
    fA4 += __shfl_xor(fA4, 16); fA5 += __shfl_xor(fA5, 16); fA6 += __shfl_xor(fA6, 16); fA7 += __shfl_xor(fA7, 16);
    fB0 += __shfl_xor(fB0, 16); fB1 += __shfl_xor(fB1, 16); fB2 += __shfl_xor(fB2, 16); fB3 += __shfl_xor(fB3, 16);
    fB4 += __shfl_xor(fB4, 16); fB5 += __shfl_xor(fB5, 16); fB6 += __shfl_xor(fB6, 16); fB7 += __shfl_xor(fB7, 16);
    fA0 += __shfl_xor(fA0, 32); fA1 += __shfl_xor(fA1, 32); fA2 += __shfl_xor(fA2, 32); fA3 += __shfl_xor(fA3, 32);
    fA4 += __shfl_xor(fA4, 32); fA5 += __shfl_xor(fA5, 32); fA6 += __shfl_xor(fA6, 32); fA7 += __shfl_xor(fA7, 32);
    fB0 += __shfl_xor(fB0, 32); fB1 += __shfl_xor(fB1, 32); fB2 += __shfl_xor(fB2, 32); fB3 += __shfl_xor(fB3, 32);
    fB4 += __shfl_xor(fB4, 32); fB5 += __shfl_xor(fB5, 32); fB6 += __shfl_xor(fB6, 32); fB7 += __shfl_xor(fB7, 32);

    // self terms (eps = 0)
    ACC8(fA, svA);
    ACC8(fB, svB);

    if (sub == 0) {
        unsigned short* hp = rowA + col * 8;      // 8 B aligned (stride 264 B)
        ((unsigned int*)hp)[0] = (unsigned int)f2bf(fA0) | ((unsigned int)f2bf(fA1) << 16);
        ((unsigned int*)hp)[1] = (unsigned int)f2bf(fA2) | ((unsigned int)f2bf(fA3) << 16);
        ((unsigned int*)(hp + 4))[0] = (unsigned int)f2bf(fA4) | ((unsigned int)f2bf(fA5) << 16);
        ((unsigned int*)(hp + 4))[1] = (unsigned int)f2bf(fA6) | ((unsigned int)f2bf(fA7) << 16);
        unsigned short* hq = rowB + col * 8;
        ((unsigned int*)hq)[0] = (unsigned int)f2bf(fB0) | ((unsigned int)f2bf(fB1) << 16);
        ((unsigned int*)hq)[1] = (unsigned int)f2bf(fB2) | ((unsigned int)f2bf(fB3) << 16);
        ((unsigned int*)(hq + 4))[0] = (unsigned int)f2bf(fB4) | ((unsigned int)f2bf(fB5) << 16);
        ((unsigned int*)(hq + 4))[1] = (unsigned int)f2bf(fB6) | ((unsigned int)f2bf(fB7) << 16);
    }
}

// ---------------- pipelined fused layer (R2-verified structure) ----------------
// 512 threads (8 waves), grid 1024 = 4 blocks/CU (32 waves/CU). Block
// pipelines tiles: while MLP'ing tile t-1 it gathers tile t. Phase A gathers
// BOTH of the wave's nodes via gather2 (doubled miss-ILP); phase B is MLP
// stage2 only. Barriers, MLP code, LDS layout verbatim from R2.

#define TILE 16
#define T_STRIDE 132
#define NT_TILES (N_NODES / TILE)   // 3125, exact
#define GRID_L 1024                 // 4 blocks/CU, all co-resident

template <bool LAST>
__global__ __launch_bounds__(512, 8) void layer_pipe(const unsigned short* __restrict__ z,
                                                     const int* __restrict__ counts,
                                                     const unsigned short* __restrict__ srcs,
                                                     const unsigned short* __restrict__ WT1,
                                                     const float* __restrict__ b1,
                                                     const unsigned short* __restrict__ WT2,
                                                     const float* __restrict__ b2,
                                                     void* __restrict__ Cout) {
    __shared__ unsigned short hbuf[2][TILE * T_STRIDE];   // double-buffered agg rows
    __shared__ unsigned short t_lds[TILE * T_STRIDE];     // MLP intermediate

    const uint4* zp = (const uint4*)z;                    // row stride = 16 uint4
    const unsigned int* sp = (const unsigned int*)srcs;   // 2 indices per uint

    int wave = threadIdx.x >> 6;     // 0..7
    int lane = threadIdx.x & 63;
    int sub  = lane >> 4;            // gather sub-slot / MLP quad
    int col  = lane & 15;            // gather col / MLP r16
    int c    = wave * 16 + col;      // MLP output column (8 waves x 16 = 128)

    int t = blockIdx.x;              // tile being gathered
    int tm = -1;                     // tile being MLP'd
    int pg = 0;                      // hbuf parity gather writes to

    while (t < NT_TILES || tm >= 0) {
        bool hasG = (t < NT_TILES);
        unsigned short* hw = hbuf[pg];
        const unsigned short* hr = hbuf[pg ^ 1];

        // ---- Phase A: MLP stage1(tm) + gather BOTH nodes of t ----
        if (tm >= 0) {
            f32x4 acc;
#pragma unroll
            for (int ii = 0; ii < 4; ++ii) acc[ii] = 0.f;
#pragma unroll
            for (int ks = 0; ks < 4; ++ks) {
                int k = ks * 32 + sub * 8;
                bf16x8 a = *(const bf16x8*)&hr[col * T_STRIDE + k];
                bf16x8 b = *(const bf16x8*)(WT1 + (size_t)c * DIM + k);
                acc = __builtin_amdgcn_mfma_f32_16x16x32_bf16(a, b, acc, 0, 0, 0);
            }
            float bv = b1[c];
#pragma unroll
            for (int ii = 0; ii < 4; ++ii)
                t_lds[(sub * 4 + ii) * T_STRIDE + c] = f2bf(fmaxf(acc[ii] + bv, 0.f));
        }
        if (hasG)
            gather2(t * TILE + wave, t * TILE + 8 + wave, zp, sp, counts, srcs,
                    sub, col, &hw[wave * T_STRIDE], &hw[(8 + wave) * T_STRIDE]);
        __syncthreads();

        // ---- Phase B: MLP stage2(tm) ----
        if (tm >= 0) {
            f32x4 acc2;
#pragma unroll
            for (int ii = 0; ii < 4; ++ii) acc2[ii] = 0.f;
#pragma unroll
            for (int ks = 0; ks < 4; ++ks) {
                int k = ks * 32 + sub * 8;
                bf16x8 a = *(const bf16x8*)&t_lds[col * T_STRIDE + k];
                bf16x8 b = *(const bf16x8*)(WT2 + (size_t)c * DIM + k);
                acc2 = __builtin_amdgcn_mfma_f32_16x16x32_bf16(a, b, acc2, 0, 0, 0);
            }
            float bv = b2[c];
#pragma unroll
            for (int ii = 0; ii < 4; ++ii) {
                int row = tm * TILE + sub * 4 + ii;   // always < N_NODES (exact tiling)
                float v = fmaxf(acc2[ii] + bv, 0.f);
                if (LAST) __builtin_nontemporal_store(v, &((float*)Cout)[(size_t)row * DIM + c]);
                else ((unsigned short*)Cout)[(size_t)row * DIM + c] = f2bf(v);
            }
        }
        __syncthreads();

        tm = hasG ? t : -1;
        pg ^= 1;
        t += GRID_L;
    }
}

// ---------------- launch ----------------

extern "C" void kernel_launch(void* const* d_in, const int* in_sizes, int n_in,
                              void* d_out, int out_size, void* d_ws, size_t ws_size,
                              hipStream_t stream) {
    const float* x   = (const float*)d_in[0];
    const float* Ws1 = (const float*)d_in[1];
    const float* bs1 = (const float*)d_in[2];
    const float* Ws2 = (const float*)d_in[3];
    const float* bs2 = (const float*)d_in[4];
    const int*   ei  = (const int*)d_in[5];   // int32 (JAX x64 disabled)
    const int* src = ei;
    const int* dst = ei + N_EDGES;
    float* out = (float*)d_out;

    char* ws = (char*)d_ws;
    size_t off = 0;
    auto carve = [&](size_t bytes) {
        void* p = ws + off;
        off += (bytes + 255) & ~(size_t)255;
        return p;
    };
    unsigned short* zA   = (unsigned short*)carve((size_t)N_NODES * DIM * 2);
    unsigned short* zB   = (unsigned short*)carve((size_t)N_NODES * DIM * 2);
    unsigned short* wt   = (unsigned short*)carve((size_t)6 * DIM * DIM * 2);
    int* counts = (int*)carve((size_t)N_NODES * 4);
    unsigned short* srcs = (unsigned short*)carve((size_t)N_NODES * CAP * 2);   // 6.4 MB buckets

    // build (XCD-partitioned hist+scatter) + cvt
    hipMemsetAsync(counts, 0, (size_t)N_NODES * 4, stream);
    build_cvt_kernel<<<BUILD_NB + CVT_NB, 256, 0, stream>>>(src, dst, counts, srcs,
                                                            x, zA, Ws1, Ws2, wt);

    unsigned short* zin = zA;
    unsigned short* znext = zB;
    for (int l = 0; l < N_LAYERS; ++l) {
        if (l == N_LAYERS - 1) {
            layer_pipe<true><<<GRID_L, 512, 0, stream>>>(
                zin, counts, srcs, wt + (size_t)l * DIM * DIM, bs1 + (size_t)l * DIM,
                wt + (size_t)(3 + l) * DIM * DIM, bs2 + (size_t)l * DIM, out);
        } else {
            layer_pipe<false><<<GRID_L, 512, 0, stream>>>(
                zin, counts, srcs, wt + (size_t)l * DIM * DIM, bs1 + (size_t)l * DIM,
                wt + (size_t)(3 + l) * DIM * DIM, bs2 + (size_t)l * DIM, znext);
            unsigned short* tmp = zin; zin = znext; znext = tmp;
        }
    }
}